// Round 12
// baseline (1428.910 us; speedup 1.0000x reference)
//
#include <hip/hip_runtime.h>

// ---------------- common helpers ----------------
typedef int    i32x4 __attribute__((ext_vector_type(4)));
typedef float  f32x4 __attribute__((ext_vector_type(4)));
typedef __bf16 bf16x8 __attribute__((ext_vector_type(8)));
typedef unsigned int u32;
typedef unsigned short u16;

#define SCALEF 0.08838834764831845f   // 1/sqrt(128)
#define EPSF 1e-5f

__device__ __forceinline__ u16 f2bf(float f) {
  u32 u = __float_as_uint(f);
  u32 r = (u + 0x7fffu + ((u >> 16) & 1u)) >> 16;  // RNE
  return (u16)r;
}
__device__ __forceinline__ float bf2f(u16 h) { return __uint_as_float(((u32)h) << 16); }
__device__ __forceinline__ u32 pack2(float a, float b) {
  return (u32)f2bf(a) | ((u32)f2bf(b) << 16);
}

__device__ __forceinline__ void gload16(const u16* g, u16* l) {
  __builtin_amdgcn_global_load_lds(
      (const __attribute__((address_space(1))) void*)g,
      (__attribute__((address_space(3))) void*)l, 16, 0, 0);
}

// ============ m201-faithful 256-tile 8-phase GEMM (R7 schedule): C = A * B^T ============
// BM=256, BN=NF*64, BK=64, 8 waves (2M x 4N). Row-major [128][64] LDS halves, XOR swizzle.
// NF=4: 4 phases x 16 MFMA / K-tile. NF=2: 2 phases x 16 MFMA. Counted vmcnt never 0.
// Column-major bijective XCD chunking.
// OUT=0: fp32 (+bias split +res)   OUT=2: swiglu-paired bf16 (W1|W3 interleaved)
// OUT=3: QKV mode — Q: +bias, RoPE, scatter->qbf(Cv); K: RoPE->kout; V->vout;
//        prompt K/V raw->pout; prompt-Q blocks early-return. Region/row boundaries
//        (4096/8192 cols, 2048 rows) are 256-aligned -> block-uniform branches.

#define G_PHASE(MFMAS) \
  __builtin_amdgcn_s_barrier(); \
  __builtin_amdgcn_s_setprio(1); \
  MFMAS \
  __builtin_amdgcn_s_setprio(0); \
  __builtin_amdgcn_s_barrier();

#define MM(KH, MB, MI, NI) \
  acc[(MB)+(MI)][NI] = __builtin_amdgcn_mfma_f32_16x16x32_bf16( \
      aa[KH][MI], bb[KH][NI], acc[(MB)+(MI)][NI], 0, 0, 0);

#define MM8(MB, NI) MM(0,MB,0,NI) MM(0,MB,1,NI) MM(0,MB,2,NI) MM(0,MB,3,NI) \
                    MM(1,MB,0,NI) MM(1,MB,1,NI) MM(1,MB,2,NI) MM(1,MB,3,NI)

#define RDA4(P, KH, MG) \
  aa[KH][0] = *(const bf16x8*)(pAk[P][KH] + ((MG)*4+0)*2048); \
  aa[KH][1] = *(const bf16x8*)(pAk[P][KH] + ((MG)*4+1)*2048); \
  aa[KH][2] = *(const bf16x8*)(pAk[P][KH] + ((MG)*4+2)*2048); \
  aa[KH][3] = *(const bf16x8*)(pAk[P][KH] + ((MG)*4+3)*2048);

#define RDB1(P, NI) \
  bb[0][NI] = *(const bf16x8*)(pBk[P][0] + (NI)*2048); \
  bb[1][NI] = *(const bf16x8*)(pBk[P][1] + (NI)*2048);

#define STAGE_A(P, HH, KT) \
  gload16(sA + ((HH)*2+0)*lda64 + (long)(KT)*64, (u16*)(lds + (P)*BUFB + (HH)*16384 + w*1024)); \
  gload16(sA + ((HH)*2+1)*lda64 + (long)(KT)*64, (u16*)(lds + (P)*BUFB + (HH)*16384 + 8192 + w*1024));

#define STAGE_B(P, HH, KT) \
  gload16(sB + ((HH)*2+0)*ldb64 + (long)(KT)*64, (u16*)(lds + (P)*BUFB + 32768 + (HH)*16384 + w*1024)); \
  gload16(sB + ((HH)*2+1)*ldb64 + (long)(KT)*64, (u16*)(lds + (P)*BUFB + 32768 + (HH)*16384 + 8192 + w*1024));

#define GEMM_TILE(P, PN, TA, TC) \
  RDA4(P,0,0) RDA4(P,1,0) \
  RDB1(P,0) RDB1(P,1) \
  STAGE_A(PN, 1, TA) \
  G_PHASE(MM8(0,0) MM8(0,1)) \
  RDB1(P,2) RDB1(P,3) \
  G_PHASE(MM8(0,2) MM8(0,3)) \
  RDA4(P,0,1) RDA4(P,1,1) \
  STAGE_B(P, 0, TC) \
  G_PHASE(MM8(4,0) MM8(4,1)) \
  STAGE_B(P, 1, TC) \
  STAGE_A(P, 0, TC) \
  asm volatile("s_waitcnt vmcnt(6)" ::: "memory"); \
  G_PHASE(MM8(4,2) MM8(4,3))

#define GEMM_TILE2(P, PN, TA, TC) \
  RDA4(P,0,0) RDA4(P,1,0) \
  RDB1(P,0) RDB1(P,1) \
  STAGE_A(PN, 0, TA) \
  STAGE_A(PN, 1, TA) \
  G_PHASE(MM8(0,0) MM8(0,1)) \
  RDA4(P,0,1) RDA4(P,1,1) \
  STAGE_B(P, 0, TC) \
  asm volatile("s_waitcnt vmcnt(2)" ::: "memory"); \
  G_PHASE(MM8(4,0) MM8(4,1))

template<int NF, int OUT>   // NF=4 -> BN=256 ; NF=2 -> BN=128
__global__ __launch_bounds__(512, 2) void gemm256(
    const u16* __restrict__ A, const u16* __restrict__ B, void* Cv,
    const float* __restrict__ bias, const float* __restrict__ bias2, int nsplit,
    const float* res, int K, int lda, int ldb, int ldc,
    u16* __restrict__ kout, u16* __restrict__ vout, u16* __restrict__ pout,
    const float* __restrict__ fcos, const float* __restrict__ fsin)
{
  extern __shared__ char lds[];
  constexpr int BN = NF * 64;
  constexpr int BUFB = (NF == 4) ? 65536 : 49152;   // A 32KB + B 32/16KB

  const int tid = threadIdx.x, w = tid >> 6, l = tid & 63;
  const int wm = w >> 2, wn = w & 3;

  // bijective XCD-chunked swizzle over COLUMN-MAJOR linear index
  const int gy = gridDim.y;
  const int nwg = gridDim.x * gy;
  const int orig = blockIdx.y * gridDim.x + blockIdx.x;
  const int q = nwg >> 3, r = nwg & 7;
  const int xcd = orig & 7, sidx = orig >> 3;
  const int wg = (xcd < r ? xcd * (q + 1) : r * (q + 1) + (xcd - r) * q) + sidx;
  const int bx = wg / gy, by = wg % gy;
  const long row0 = (long)by * 256, col0 = (long)bx * BN;

  if constexpr (OUT == 3) {
    if (col0 < 4096 && row0 >= 2048) return;   // prompt-Q blocks: output unused
  }

  // ---- LDS read base pointers (swizzled) ----
  const int g4 = l >> 4, h8 = l & 7, r16 = l & 15;
  const int cs0 = ((g4 ^ h8) << 4);
  const int cs1 = cs0 ^ 64;
  const char* pAk[2][2];
  const char* pBk[2][2];
  {
    const int aoff = wm * 16384 + r16 * 128;
    const int boff = 32768 + ((NF == 4) ? ((wn >> 1) * 16384 + (wn & 1) * 8192)
                                        : (wn * 4096)) + r16 * 128;
    pAk[0][0] = lds + aoff + cs0;        pAk[0][1] = lds + aoff + cs1;
    pAk[1][0] = pAk[0][0] + BUFB;        pAk[1][1] = pAk[0][1] + BUFB;
    pBk[0][0] = lds + boff + cs0;        pBk[0][1] = lds + boff + cs1;
    pBk[1][0] = pBk[0][0] + BUFB;        pBk[1][1] = pBk[0][1] + BUFB;
  }

  // ---- staging: pre-swizzled per-lane global source, linear LDS dest ----
  const long ldaL = lda, ldbL = ldb;
  const long lda64 = ldaL * 64, ldb64 = ldbL * 64;
  const int srow = w * 8 + (l >> 3);
  const int scol = ((h8 ^ (l >> 3)) << 3);
  const u16* sA = A + (row0 + srow) * ldaL + scol;
  const u16* sB = B + (col0 + srow) * ldbL + scol;

  f32x4 acc[8][4];
  #pragma unroll
  for (int m = 0; m < 8; m++)
    #pragma unroll
    for (int n = 0; n < 4; n++)
      #pragma unroll
      for (int j = 0; j < 4; j++) acc[m][n][j] = 0.f;

  bf16x8 aa[2][4], bb[2][4];

  const int NT = K >> 6;
  if constexpr (NF == 4) {
    STAGE_A(0,0,0) STAGE_A(0,1,0) STAGE_B(0,0,0) STAGE_B(0,1,0)
    STAGE_B(1,0,1) STAGE_B(1,1,1) STAGE_A(1,0,1)
    asm volatile("s_waitcnt vmcnt(6)" ::: "memory");
    __builtin_amdgcn_s_barrier();
    for (int t = 0; t < NT; t += 2) {
      const int ta = (t + 1 < NT) ? t + 1 : NT - 1;
      const int tb = (t + 2 < NT) ? t + 2 : NT - 1;
      const int tc = (t + 3 < NT) ? t + 3 : NT - 1;
      GEMM_TILE(0, 1, ta, tb)
      GEMM_TILE(1, 0, tb, tc)
    }
  } else {
    STAGE_A(0,0,0) STAGE_A(0,1,0) STAGE_B(0,0,0)
    STAGE_B(1,0,1)
    asm volatile("s_waitcnt vmcnt(2)" ::: "memory");
    __builtin_amdgcn_s_barrier();
    for (int t = 0; t < NT; t += 2) {
      const int ta = (t + 1 < NT) ? t + 1 : NT - 1;
      const int tb = (t + 2 < NT) ? t + 2 : NT - 1;
      const int tc = (t + 3 < NT) ? t + 3 : NT - 1;
      GEMM_TILE2(0, 1, ta, tb)
      GEMM_TILE2(1, 0, tb, tc)
    }
  }

  // ---- epilogue: C/D layout col = lane&15, row = (lane>>4)*4 + j [m89] ----
  const int cc = l & 15, cr = (l >> 4) * 4;
  if constexpr (OUT == 3) {
    const int reg = (int)(col0 >> 12);        // 0=Q, 1=K, 2=V (block-uniform)
    const bool isP = (row0 >= 2048);          // prompt rows (block-uniform)
    #pragma unroll
    for (int mf = 0; mf < 8; mf++) {
      const long rrow = row0 + wm * 128 + mf * 16 + cr;
      #pragma unroll
      for (int nf = 0; nf < 4; nf++) {
        const long ccol = col0 + wn * 64 + nf * 16 + cc;
        #pragma unroll
        for (int j = 0; j < 4; j++) {
          float v = acc[mf][nf][j];
          const long grow = rrow + j;
          if (reg == 0) {                      // Q (token only)
            v += bias[ccol];
            const int s = (int)(grow & 511), bb_ = (int)(grow >> 9);
            const int d = (int)(ccol & 127), h = (int)((ccol >> 7) & 31);
            const int ip = d >> 1;
            const float c = fcos[s * 64 + ip], sn = fsin[s * 64 + ip];
            const float other = __shfl_xor(v, 1);
            const float rr = (d & 1) ? (other * sn + v * c) : (v * c - other * sn);
            ((u16*)Cv)[((long)(bb_ * 32 + h) * 512 + s) * 128 + d] = f2bf(rr);
          } else if (reg == 1) {               // K
            if (!isP) {
              const int s = (int)(grow & 511), bb_ = (int)(grow >> 9);
              const int d = (int)(ccol & 127), h = (int)((ccol >> 7) & 31);
              const int ip = d >> 1;
              const float c = fcos[s * 64 + ip], sn = fsin[s * 64 + ip];
              const float other = __shfl_xor(v, 1);
              const float rr = (d & 1) ? (other * sn + v * c) : (v * c - other * sn);
              kout[((long)(bb_ * 32 + h) * 512 + s) * 128 + d] = f2bf(rr);
            } else {
              pout[(grow - 2048) * 8192 + (ccol - 4096)] = f2bf(v);
            }
          } else {                             // V
            if (!isP) vout[grow * 4096 + (ccol - 8192)] = f2bf(v);
            else      pout[(grow - 2048) * 8192 + 4096 + (ccol - 8192)] = f2bf(v);
          }
        }
      }
    }
  } else {
    #pragma unroll
    for (int mf = 0; mf < 8; mf++) {
      const long rrow = row0 + wm * 128 + mf * 16 + cr;
      if constexpr (OUT == 2) {
        #pragma unroll
        for (int nfp = 0; nfp < NF / 2; nfp++) {
          const long outc = (col0 >> 1) + wn * 32 + nfp * 16 + cc;
          const float b1 = bias[outc], b3 = bias2[outc];
          #pragma unroll
          for (int j = 0; j < 4; j++) {
            const float v1 = acc[mf][2 * nfp][j] + b1;
            const float v3 = acc[mf][2 * nfp + 1][j] + b3;
            const float o = v1 / (1.f + __expf(-v1)) * v3;
            ((u16*)Cv)[(rrow + j) * ldc + outc] = f2bf(o);
          }
        }
      } else {
        #pragma unroll
        for (int nf = 0; nf < 4 && nf < NF; nf++) {
          const long ccol = col0 + wn * (NF * 16) + nf * 16 + cc;
          float bb2 = 0.f;
          if (bias) bb2 = (ccol < nsplit) ? bias[ccol] : (bias2 ? bias2[ccol - nsplit] : 0.f);
          #pragma unroll
          for (int j = 0; j < 4; j++) {
            const long off = (rrow + j) * ldc + ccol;
            float v = acc[mf][nf][j] + bb2;
            if (res) v += res[off];
            ((float*)Cv)[off] = v;
          }
        }
      }
    }
  }
}

// ---------------- bf16 GEMM: C = A * B^T (128x128 tile) — scores / PV ----------------
// EPI=1: bf16(acc*scale + Cadd)   EPI=2: bf16(acc*scale)
// causal!=0: skip fully-masked tiles.  kvar!=0: K_eff=(by+1)*128 (causal PV).
template<int EPI>
__global__ __launch_bounds__(256) void gemm_bt(
    const u16* __restrict__ A, const u16* __restrict__ B,
    float* __restrict__ Cf, u16* __restrict__ Cbf, const float* __restrict__ Cadd,
    int K, int lda, int ldb, int ldc, float scale,
    long sAb, long sBb, int cInnerN, long cSO, long cSI, int causal, int kvar)
{
  if (causal && blockIdx.x > blockIdx.y) return;
  const int Keff = kvar ? (int)(blockIdx.y + 1) * 128 : K;

  __shared__ u16 As[128*32] __attribute__((aligned(16)));
  __shared__ u16 Bs[128*32] __attribute__((aligned(16)));
  const int tid  = threadIdx.x;
  const int wave = tid >> 6, lane = tid & 63;
  const int wm = wave >> 1, wn = wave & 1;
  const int z = blockIdx.z;
  const u16* Ab = A + (long)z * sAb;
  const u16* Bb = B + (long)z * sBb;
  const long cb = (long)(z / cInnerN) * cSO + (long)(z % cInnerN) * cSI;

  const int sr = lane >> 2;
  const int sc = (lane & 3) * 8;
  const int c0 = wave * 2, c1 = wave * 2 + 1;
  const u16* gA0 = Ab + (long)(blockIdx.y * 128 + c0 * 16 + sr) * lda + sc;
  const u16* gA1 = Ab + (long)(blockIdx.y * 128 + c1 * 16 + sr) * lda + sc;
  const u16* gB0 = Bb + (long)(blockIdx.x * 128 + c0 * 16 + sr) * ldb + sc;
  const u16* gB1 = Bb + (long)(blockIdx.x * 128 + c1 * 16 + sr) * ldb + sc;
  u16* lA0 = &As[c0 * 512]; u16* lA1 = &As[c1 * 512];
  u16* lB0 = &Bs[c0 * 512]; u16* lB1 = &Bs[c1 * 512];

  f32x4 acc[4][4];
  #pragma unroll
  for (int m = 0; m < 4; m++)
    #pragma unroll
    for (int n = 0; n < 4; n++)
      #pragma unroll
      for (int j = 0; j < 4; j++) acc[m][n][j] = 0.f;

  const int fr  = lane & 15;
  const int fg8 = (lane >> 4) * 8;

  for (int k0 = 0; k0 < Keff; k0 += 32) {
    __syncthreads();
    gload16(gA0 + k0, lA0);
    gload16(gA1 + k0, lA1);
    gload16(gB0 + k0, lB0);
    gload16(gB1 + k0, lB1);
    __syncthreads();

    bf16x8 af[4], bfr[4];
    #pragma unroll
    for (int m = 0; m < 4; m++)
      af[m] = *(const bf16x8*)&As[(wm * 64 + m * 16 + fr) * 32 + fg8];
    #pragma unroll
    for (int n = 0; n < 4; n++)
      bfr[n] = *(const bf16x8*)&Bs[(wn * 64 + n * 16 + fr) * 32 + fg8];

    #pragma unroll
    for (int m = 0; m < 4; m++)
      #pragma unroll
      for (int n = 0; n < 4; n++)
        acc[m][n] = __builtin_amdgcn_mfma_f32_16x16x32_bf16(af[m], bfr[n], acc[m][n], 0, 0, 0);
  }

  const int cc = lane & 15, cr = (lane >> 4) * 4;
  #pragma unroll
  for (int m = 0; m < 4; m++) {
    const int row = blockIdx.y * 128 + wm * 64 + m * 16 + cr;
    #pragma unroll
    for (int n = 0; n < 4; n++) {
      const int col = blockIdx.x * 128 + wn * 64 + n * 16 + cc;
      #pragma unroll
      for (int j = 0; j < 4; j++) {
        const long off = cb + (long)(row + j) * ldc + col;
        const float v = acc[m][n][j] * scale;
        if constexpr (EPI == 0)      Cf[off] = v;
        else if constexpr (EPI == 1) Cbf[off] = f2bf(v + Cadd[off]);
        else                         Cbf[off] = f2bf(v);
      }
    }
  }
}

// ---------------- low-VGPR pack core: 4 rows/block, i-unroll 4 ----------------
__device__ __forceinline__ void pack_rows4(const float* __restrict__ w,
    const float* __restrict__ l2, const float* __restrict__ l1,
    u16* __restrict__ out, long srcRow0, long outRow0, int K) {
  __shared__ float l2s[4][16];
  if (threadIdx.x < 64) l2s[threadIdx.x >> 4][threadIdx.x & 15] =
      l2[(srcRow0 + (threadIdx.x >> 4)) * 16 + (threadIdx.x & 15)];
  __syncthreads();
  for (int c = threadIdx.x * 4; c < K; c += 1024) {
    float4 v0 = *(const float4*)(w + (srcRow0 + 0) * K + c);
    float4 v1 = *(const float4*)(w + (srcRow0 + 1) * K + c);
    float4 v2 = *(const float4*)(w + (srcRow0 + 2) * K + c);
    float4 v3 = *(const float4*)(w + (srcRow0 + 3) * K + c);
    #pragma unroll 4
    for (int i = 0; i < 16; i++) {
      const float4 lv = *(const float4*)(l1 + (long)i * K + c);
      const float a0 = l2s[0][i], a1 = l2s[1][i], a2 = l2s[2][i], a3 = l2s[3][i];
      v0.x += a0 * lv.x; v0.y += a0 * lv.y; v0.z += a0 * lv.z; v0.w += a0 * lv.w;
      v1.x += a1 * lv.x; v1.y += a1 * lv.y; v1.z += a1 * lv.z; v1.w += a1 * lv.w;
      v2.x += a2 * lv.x; v2.y += a2 * lv.y; v2.z += a2 * lv.z; v2.w += a2 * lv.w;
      v3.x += a3 * lv.x; v3.y += a3 * lv.y; v3.z += a3 * lv.z; v3.w += a3 * lv.w;
    }
    uint2 p0, p1, p2, p3;
    p0.x = pack2(v0.x, v0.y); p0.y = pack2(v0.z, v0.w);
    p1.x = pack2(v1.x, v1.y); p1.y = pack2(v1.z, v1.w);
    p2.x = pack2(v2.x, v2.y); p2.y = pack2(v2.z, v2.w);
    p3.x = pack2(v3.x, v3.y); p3.y = pack2(v3.z, v3.w);
    *(uint2*)(out + (outRow0 + 0) * K + c) = p0;
    *(uint2*)(out + (outRow0 + 1) * K + c) = p1;
    *(uint2*)(out + (outRow0 + 2) * K + c) = p2;
    *(uint2*)(out + (outRow0 + 3) * K + c) = p3;
  }
}

__global__ __launch_bounds__(256) void pack4(
    const float* w0, const float* a0, const float* b0, u16* o0,
    const float* w1, const float* a1, const float* b1, u16* o1,
    const float* w2, const float* a2, const float* b2, u16* o2,
    const float* w3, const float* a3, const float* b3, u16* o3) {
  const int sel = blockIdx.x >> 10;
  const long row0 = (long)(blockIdx.x & 1023) * 4;
  const float* w;  const float* l2; const float* l1; u16* out;
  switch (sel) {
    case 0:  w = w0; l2 = a0; l1 = b0; out = o0; break;
    case 1:  w = w1; l2 = a1; l1 = b1; out = o1; break;
    case 2:  w = w2; l2 = a2; l1 = b2; out = o2; break;
    default: w = w3; l2 = a3; l1 = b3; out = o3; break;
  }
  pack_rows4(w, l2, l1, out, row0, row0, 4096);
}

__global__ __launch_bounds__(256) void packw4(const float* __restrict__ w,
    const float* __restrict__ l2, const float* __restrict__ l1,
    u16* __restrict__ out, int K) {
  const long row0 = (long)blockIdx.x * 4;
  pack_rows4(w, l2, l1, out, row0, row0, K);
}

__global__ __launch_bounds__(256) void packw13_4(const float* __restrict__ w1,
    const float* __restrict__ l2_1, const float* __restrict__ l1_1,
    const float* __restrict__ w3,
    const float* __restrict__ l2_3, const float* __restrict__ l1_3,
    u16* __restrict__ out) {
  const long row0 = (long)blockIdx.x * 4;
  const int s = ((int)row0 >> 4) & 1;
  const long src0 = (row0 >> 5) * 16 + (row0 & 15);
  pack_rows4(s ? w3 : w1, s ? l2_3 : l2_1, s ? l1_3 : l1_1, out, src0, row0, 4096);
}

// ---------------- prep: rmsnorm tokens + prompt cvt + zero pad (grid 2304) ----------------
__global__ __launch_bounds__(256) void prep(const float* __restrict__ x, const float* __restrict__ w,
                                            const float* __restrict__ prompt, u16* __restrict__ out) {
  const int bid = blockIdx.x;
  if (bid < 2048) {
    const float4* xr = (const float4*)(x + (long)bid * 4096);
    const float4* wr = (const float4*)w;
    float4 v[4];
    float ss = 0.f;
    #pragma unroll
    for (int j = 0; j < 4; j++) {
      v[j] = xr[threadIdx.x + j * 256];
      ss += v[j].x * v[j].x + v[j].y * v[j].y + v[j].z * v[j].z + v[j].w * v[j].w;
    }
    #pragma unroll
    for (int off = 32; off; off >>= 1) ss += __shfl_xor(ss, off);
    __shared__ float wsum[4];
    if ((threadIdx.x & 63) == 0) wsum[threadIdx.x >> 6] = ss;
    __syncthreads();
    const float sc = rsqrtf((wsum[0] + wsum[1] + wsum[2] + wsum[3]) * (1.f / 4096.f) + EPSF);
    u16* orow = out + (long)bid * 4096;
    #pragma unroll
    for (int j = 0; j < 4; j++) {
      float4 wv = wr[threadIdx.x + j * 256];
      int idx = (threadIdx.x + j * 256) * 4;
      uint2 p;
      p.x = pack2(v[j].x * sc * wv.x, v[j].y * sc * wv.y);
      p.y = pack2(v[j].z * sc * wv.z, v[j].w * sc * wv.w);
      *(uint2*)&orow[idx] = p;
    }
  } else if (bid < 2088) {
    const int r = bid - 2048;
    const float4* src = (const float4*)(prompt + (long)r * 4096);
    u16* dst = out + (long)(2048 + r) * 4096;
    #pragma unroll
    for (int j = 0; j < 4; j++) {
      float4 v = src[threadIdx.x + j * 256];
      int idx = (threadIdx.x + j * 256) * 4;
      uint2 p; p.x = pack2(v.x, v.y); p.y = pack2(v.z, v.w);
      *(uint2*)&dst[idx] = p;
    }
  } else {
    u16* dst = out + (long)bid * 4096 + threadIdx.x * 16;
    i32x4 z; z[0] = 0; z[1] = 0; z[2] = 0; z[3] = 0;
    *(i32x4*)dst = z;
    *(i32x4*)(dst + 8) = z;
  }
}

// ---------------- fused prompt LoRA subtract on pbuf (grid 40) ----------------
__global__ __launch_bounds__(256) void lorap(const u16* __restrict__ Ap,
    const float* __restrict__ L1k, const float* __restrict__ L2k,
    const float* __restrict__ L1v, const float* __restrict__ L2v,
    u16* __restrict__ pbuf) {
  const int row = blockIdx.x;
  const int lane = threadIdx.x & 63, wave = threadIdx.x >> 6;
  __shared__ float tk[16], tv[16];
  const u16* a = Ap + (long)row * 4096;
  {
    const float* k0 = L1k + (long)(wave * 4 + 0) * 4096;
    const float* k1 = L1k + (long)(wave * 4 + 1) * 4096;
    const float* k2 = L1k + (long)(wave * 4 + 2) * 4096;
    const float* k3 = L1k + (long)(wave * 4 + 3) * 4096;
    const float* v0 = L1v + (long)(wave * 4 + 0) * 4096;
    const float* v1 = L1v + (long)(wave * 4 + 1) * 4096;
    const float* v2 = L1v + (long)(wave * 4 + 2) * 4096;
    const float* v3 = L1v + (long)(wave * 4 + 3) * 4096;
    float ak0 = 0, ak1 = 0, ak2 = 0, ak3 = 0;
    float av0 = 0, av1 = 0, av2 = 0, av3 = 0;
    for (int k = lane; k < 4096; k += 64) {
      const float av = bf2f(a[k]);
      ak0 += av * k0[k]; ak1 += av * k1[k]; ak2 += av * k2[k]; ak3 += av * k3[k];
      av0 += av * v0[k]; av1 += av * v1[k]; av2 += av * v2[k]; av3 += av * v3[k];
    }
    #pragma unroll
    for (int off = 32; off; off >>= 1) {
      ak0 += __shfl_down(ak0, off); ak1 += __shfl_down(ak1, off);
      ak2 += __shfl_down(ak2, off); ak3 += __shfl_down(ak3, off);
      av0 += __shfl_down(av0, off); av1 += __shfl_down(av1, off);
      av2 += __shfl_down(av2, off); av3 += __shfl_down(av3, off);
    }
    if (lane == 0) {
      tk[wave * 4 + 0] = ak0; tk[wave * 4 + 1] = ak1;
      tk[wave * 4 + 2] = ak2; tk[wave * 4 + 3] = ak3;
      tv[wave * 4 + 0] = av0; tv[wave * 4 + 1] = av1;
      tv[wave * 4 + 2] = av2; tv[wave * 4 + 3] = av3;
    }
  }
  __syncthreads();
  u16* pr = pbuf + (long)row * 8192;
  for (int col = threadIdx.x; col < 4096; col += 256) {
    float addk = 0.f, addv = 0.f;
    const float* lk = L2k + (long)col * 16;
    const float* lv = L2v + (long)col * 16;
    #pragma unroll
    for (int r = 0; r < 16; r++) { addk += tk[r] * lk[r]; addv += tv[r] * lv[r]; }
    pr[col] = f2bf(bf2f(pr[col]) - addk);
    pr[4096 + col] = f2bf(bf2f(pr[4096 + col]) - addv);
  }
}

// ---------------- layout: vtrans (8192 blocks, from vbuf) + extract_prompt (40) ----------------
__global__ __launch_bounds__(256) void layout(const u16* __restrict__ vbuf, const u16* __restrict__ pbuf,
    u16* __restrict__ vt, u16* __restrict__ pk, u16* __restrict__ pv) {
  const int bid = blockIdx.x;
  if (bid < 8192) {
    const int s0 = (bid & 15) * 32, d0 = ((bid >> 4) & 3) * 32, bh = bid >> 6;
    const int b = bh >> 5, h = bh & 31;
    __shared__ u16 tile[32][33];
    const int tx = threadIdx.x & 31, ty = threadIdx.x >> 5;
    #pragma unroll
    for (int j = 0; j < 4; j++) {
      const int s = s0 + ty + j * 8;
      tile[ty + j * 8][tx] = vbuf[(long)(b * 512 + s) * 4096 + h * 128 + d0 + tx];
    }
    __syncthreads();
    #pragma unroll
    for (int j = 0; j < 4; j++) {
      const int d = d0 + ty + j * 8;
      vt[((long)bh * 128 + d) * 512 + s0 + tx] = tile[tx][ty + j * 8];
    }
  } else {
    const int rp = bid - 8192;
    const int b = rp / 10, p = rp % 10;
    const u16* src = pbuf + (long)rp * 8192;
    for (int col = threadIdx.x * 2; col < 4096; col += 512) {
      const int h = col >> 7, d = col & 127;
      const long dst = ((long)(b * 32 + h) * 10 + p) * 128 + d;
      *(u32*)&pk[dst] = *(const u32*)&src[col];
      *(u32*)&pv[dst] = *(const u32*)&src[4096 + col];
    }
  }
}

// ---------------- smpa: softmax over bf16 scores (16384) + prompt attention (16384) ----------------
__global__ __launch_bounds__(256) void smpa(const u16* __restrict__ sc, u16* __restrict__ P,
    const u16* __restrict__ qbf, const u16* __restrict__ pk, const u16* __restrict__ pv,
    const float* __restrict__ gate, const float* __restrict__ ngate, float* __restrict__ attnp) {
  const int bid = blockIdx.x;
  const int lane = threadIdx.x & 63;
  if (bid < 16384) {
    const int r = bid * 4 + (threadIdx.x >> 6);
    const int q = r & 511;
    const u16* srow = sc + (long)r * 512 + lane * 8;
    i32x4 raw = *(const i32x4*)srow;
    float v[8]; float m = -3e38f;
    #pragma unroll
    for (int j = 0; j < 8; j++) {
      const u32 u = (u32)raw[j >> 1];
      const float val = bf2f((j & 1) ? (u16)(u >> 16) : (u16)u);
      const int col = lane * 8 + j;
      v[j] = (col <= q) ? val : -3e38f;
      m = fmaxf(m, v[j]);
    }
    #pragma unroll
    for (int off = 32; off; off >>= 1) m = fmaxf(m, __shfl_xor(m, off));
    float sum = 0.f;
    #pragma unroll
    for (int j = 0; j < 8; j++) { v[j] = __expf(v[j] - m); sum += v[j]; }
    #pragma unroll
    for (int off = 32; off; off >>= 1) sum += __shfl_xor(sum, off);
    const float inv = 1.f / sum;
    i32x4 o;
    o[0] = (int)pack2(v[0] * inv, v[1] * inv); o[1] = (int)pack2(v[2] * inv, v[3] * inv);
    o[2] = (int)pack2(v[4] * inv, v[5] * inv); o[3] = (int)pack2(v[6] * inv, v[7] * inv);
    *(i32x4*)(P + (long)r * 512 + lane * 8) = o;
  } else {
    const int r = (bid - 16384) * 4 + (threadIdx.x >> 6);
    const int bh = r >> 9, q = r & 511, b = bh >> 5, h = bh & 31;
    const u32 qraw = *(const u32*)&qbf[(long)r * 128 + lane * 2];
    const float q0 = bf2f((u16)qraw), q1 = bf2f((u16)(qraw >> 16));
    float s[10];
    #pragma unroll
    for (int p = 0; p < 10; p++) {
      const u32 kraw = *(const u32*)&pk[((long)bh * 10 + p) * 128 + lane * 2];
      float d = q0 * bf2f((u16)kraw) + q1 * bf2f((u16)(kraw >> 16));
      #pragma unroll
      for (int off = 32; off; off >>= 1) d += __shfl_xor(d, off);
      s[p] = d * SCALEF;
    }
    float m = s[0];
    #pragma unroll
    for (int p = 1; p < 10; p++) m = fmaxf(m, s[p]);
    float sum = 0.f;
    #pragma unroll
    for (int p = 0; p < 10; p++) { s[p] = __expf(s[p] - m); sum += s[p]; }
    const float gt = tanhf(gate[h]) * ngate[0] / sum;
    float o0 = 0.f, o1 = 0.f;
    #pragma unroll
    for (int p = 0; p < 10; p++) {
      const u32 vraw = *(const u32*)&pv[((long)bh * 10 + p) * 128 + lane * 2];
      o0 += s[p] * bf2f((u16)vraw); o1 += s[p] * bf2f((u16)(vraw >> 16));
    }
    float2 ov = make_float2(gt * o0, gt * o1);
    *(float2*)&attnp[(long)(b * 512 + q) * 4096 + h * 128 + lane * 2] = ov;
  }
}

// =====================================================================================
extern "C" void kernel_launch(void* const* d_in, const int* in_sizes, int n_in,
                              void* d_out, int out_size, void* d_ws, size_t ws_size,
                              hipStream_t stream) {
  const float* x      = (const float*)d_in[0];
  const float* prompt = (const float*)d_in[1];
  const float* fcos   = (const float*)d_in[5];
  const float* fsin   = (const float*)d_in[6];
  const float* wq     = (const float*)d_in[7];
  const float* wq_b   = (const float*)d_in[8];
  const float* wk     = (const float*)d_in[9];
  const float* wv     = (const float*)d_in[10];
  const float* wo     = (const float*)d_in[11];
  const float* wo_b   = (const float*)d_in[12];
  const float* lq1    = (const float*)d_in[13];
  const float* lq2    = (const float*)d_in[14];
  const float* lk1    = (const float*)d_in[15];
  const float* lk2    = (const float*)d_in[16];
  const float* lv1    = (const float*)d_in[17];
  const float* lv2    = (const float*)d_in[18];
  const float* lo1    = (const float*)d_in[19];
  const float* lo2    = (const float*)d_in[20];
  const float* gate   = (const float*)d_in[21];
  const float* ngate  = (const float*)d_in[22];
  const float* anw    = (const float*)d_in[23];
  const float* fnw    = (const float*)d_in[24];
  const float* w1     = (const float*)d_in[25];
  const float* w1_b   = (const float*)d_in[26];
  const float* w2     = (const float*)d_in[27];
  const float* w2_b   = (const float*)d_in[28];
  const float* w3     = (const float*)d_in[29];
  const float* w3_b   = (const float*)d_in[30];
  const float* fl1a   = (const float*)d_in[31];
  const float* fl1b   = (const float*)d_in[32];
  const float* fl2a   = (const float*)d_in[33];
  const float* fl2b   = (const float*)d_in[34];
  const float* fl3a   = (const float*)d_in[35];
  const float* fl3b   = (const float*)d_in[36];
  float* out = (float*)d_out;

  char* base = (char*)d_ws;
  u16* Wq  = (u16*)(base + 0L);          // Wq|Wk|Wv contiguous -> fused QKV B (12288 x 4096)
  u16* Wo  = (u16*)(base + 100663296L);
  u16* W13 = (u16*)(base + 134217728L);  // 22016 x 4096, w1/w3 interleaved by 16 rows
  u16* W2  = (u16*)(base + 314572800L);
  u16* Abf = (u16*)(base + 404750336L);  // 2304 x 4096 bf16 (tokens + prompt + zero pad)
  const long SP = 423624704L;
  // region X: scores16 (67MB) / obf (45MB) time-multiplexed at SP; vbuf/pbuf in same window
  u16*   scores16 = (u16*)(base + SP);
  u16*   obf      = (u16*)(base + SP);
  u16*   vbuf     = (u16*)(base + SP + 73400320L);   // 2048 x 4096 bf16 (16.8 MB)
  u16*   pbuf     = (u16*)(base + SP + 92274688L);   // 256 x 8192 bf16 (4.2 MB)
  u16*   qbf      = (u16*)(base + SP + 134217728L);
  u16*   kbf      = (u16*)(base + SP + 150994944L);
  u16*   vt       = (u16*)(base + SP + 167772160L);
  u16*   pk       = (u16*)(base + SP + 184549376L);
  u16*   pv       = (u16*)(base + SP + 184877056L);
  u16*   Pbf      = (u16*)(base + SP + 185204736L);
  float* attnp    = (float*)(base + SP + 252313600L);
  u16*   attnbf   = (u16*)(base + SP + 285868032L);
  u16*   gbf      = (u16*)(base + SP + 302645248L);
  const long TOTAL = SP + 319422464L + 131072L;
  if ((long)ws_size < TOTAL) return;

  dim3 blk(256);
  {
    auto f43 = gemm256<4, 3>; auto f42 = gemm256<4, 2>; auto f2 = gemm256<2, 0>;
    (void)hipFuncSetAttribute((const void*)f43, hipFuncAttributeMaxDynamicSharedMemorySize, 131072);
    (void)hipFuncSetAttribute((const void*)f42, hipFuncAttributeMaxDynamicSharedMemorySize, 131072);
    (void)hipFuncSetAttribute((const void*)f2,  hipFuncAttributeMaxDynamicSharedMemorySize, 98304);
  }

  // 1) pack weights (LoRA folded): W' = W + l2 @ l1
  pack4<<<4096, blk, 0, stream>>>(wq, lq2, lq1, Wq,
                                  wk, lk2, lk1, Wq + 16777216L,
                                  wv, lv2, lv1, Wq + 33554432L,
                                  wo, lo2, lo1, Wo);
  packw13_4<<<5504, blk, 0, stream>>>(w1, fl1b, fl1a, w3, fl3b, fl3a, W13);
  packw4<<<1024, blk, 0, stream>>>(w2, fl2b, fl2a, W2, 11008);

  // 2) A matrix: rms(x) tokens + prompt cvt + zero pad
  prep<<<2304, blk, 0, stream>>>(x, anw, prompt, Abf);

  // 3) fused QKV projection with RoPE+scatter epilogue: Q->qbf, K->kbf, V->vbuf,
  //    prompt K/V -> pbuf (raw). Prompt-Q blocks self-skip.
  gemm256<4, 3><<<dim3(48, 9), 512, 131072, stream>>>(Abf, Wq, qbf, wq_b, nullptr, 0,
      nullptr, 4096, 4096, 4096, 0, kbf, vbuf, pbuf, fcos, fsin);
  // subtract LoRA from prompt K/V (reference has no LoRA on prompt)
  lorap<<<40, blk, 0, stream>>>(Abf + 2048L * 4096, lk1, lk2, lv1, lv2, pbuf);

  // 4) V transpose + prompt extract
  layout<<<8232, blk, 0, stream>>>(vbuf, pbuf, vt, pk, pv);

  // 5) attention (causal-aware; bf16 scores)
  gemm_bt<2><<<dim3(4, 4, 128), blk, 0, stream>>>(qbf, kbf, nullptr, scores16, nullptr,
      128, 128, 128, 512, SCALEF, 65536L, 65536L, 1, 262144L, 0, 1, 0);
  smpa<<<32768, blk, 0, stream>>>(scores16, Pbf, qbf, pk, pv, gate, ngate, attnp);
  gemm_bt<1><<<dim3(1, 4, 128), blk, 0, stream>>>(Pbf, vt, nullptr, attnbf, attnp,
      512, 512, 512, 4096, 1.f, 262144L, 65536L, 32, 2097152L, 128L, 0, 1);

  // 6) output projection (+bias +residual x) -> h2 in d_out
  gemm256<2, 0><<<dim3(32, 8), 512, 98304, stream>>>(attnbf, Wo, out, wo_b, nullptr, 1 << 30,
      x, 4096, 4096, 4096, 4096, nullptr, nullptr, nullptr, nullptr, nullptr);

  // 7) FFN: rms -> fused W1|W3 GEMM with swiglu epilogue -> obf -> W2 (+bias +res h2)
  prep<<<2048, blk, 0, stream>>>(out, fnw, nullptr, gbf);
  gemm256<4, 2><<<dim3(86, 8), 512, 131072, stream>>>(gbf, W13, obf, w1_b, w3_b, 0,
      nullptr, 4096, 4096, 4096, 11008, nullptr, nullptr, nullptr, nullptr, nullptr);
  gemm256<2, 0><<<dim3(32, 8), 512, 98304, stream>>>(obf, W2, out, w2_b, nullptr, 1 << 30,
      out, 11008, 11008, 11008, 4096, nullptr, nullptr, nullptr, nullptr, nullptr);
}

// Round 13
// 1376.752 us; speedup vs baseline: 1.0379x; 1.0379x over previous
//
#include <hip/hip_runtime.h>

// ---------------- common helpers ----------------
typedef int    i32x4 __attribute__((ext_vector_type(4)));
typedef float  f32x4 __attribute__((ext_vector_type(4)));
typedef __bf16 bf16x8 __attribute__((ext_vector_type(8)));
typedef unsigned int u32;
typedef unsigned short u16;

#define SCALEF 0.08838834764831845f   // 1/sqrt(128)
#define EPSF 1e-5f

__device__ __forceinline__ u16 f2bf(float f) {
  u32 u = __float_as_uint(f);
  u32 r = (u + 0x7fffu + ((u >> 16) & 1u)) >> 16;  // RNE
  return (u16)r;
}
__device__ __forceinline__ float bf2f(u16 h) { return __uint_as_float(((u32)h) << 16); }
__device__ __forceinline__ u32 pack2(float a, float b) {
  return (u32)f2bf(a) | ((u32)f2bf(b) << 16);
}

__device__ __forceinline__ void gload16(const u16* g, u16* l) {
  __builtin_amdgcn_global_load_lds(
      (const __attribute__((address_space(1))) void*)g,
      (__attribute__((address_space(3))) void*)l, 16, 0, 0);
}

// ============ m201-faithful 256-tile 8-phase GEMM (R7 schedule): C = A * B^T ============
// BM=256, BN=NF*64, BK=64, 8 waves (2M x 4N). Row-major [128][64] LDS halves, XOR swizzle.
// NF=4: 4 phases x 16 MFMA / K-tile. NF=2: 2 phases x 16 MFMA. Counted vmcnt never 0.
// Column-major bijective XCD chunking.
// OUT=0: fp32 (+bias split +res)  OUT=1: bf16 (+bias split)  OUT=2: swiglu-paired bf16

#define G_PHASE(MFMAS) \
  __builtin_amdgcn_s_barrier(); \
  __builtin_amdgcn_s_setprio(1); \
  MFMAS \
  __builtin_amdgcn_s_setprio(0); \
  __builtin_amdgcn_s_barrier();

#define MM(KH, MB, MI, NI) \
  acc[(MB)+(MI)][NI] = __builtin_amdgcn_mfma_f32_16x16x32_bf16( \
      aa[KH][MI], bb[KH][NI], acc[(MB)+(MI)][NI], 0, 0, 0);

#define MM8(MB, NI) MM(0,MB,0,NI) MM(0,MB,1,NI) MM(0,MB,2,NI) MM(0,MB,3,NI) \
                    MM(1,MB,0,NI) MM(1,MB,1,NI) MM(1,MB,2,NI) MM(1,MB,3,NI)

#define RDA4(P, KH, MG) \
  aa[KH][0] = *(const bf16x8*)(pAk[P][KH] + ((MG)*4+0)*2048); \
  aa[KH][1] = *(const bf16x8*)(pAk[P][KH] + ((MG)*4+1)*2048); \
  aa[KH][2] = *(const bf16x8*)(pAk[P][KH] + ((MG)*4+2)*2048); \
  aa[KH][3] = *(const bf16x8*)(pAk[P][KH] + ((MG)*4+3)*2048);

#define RDB1(P, NI) \
  bb[0][NI] = *(const bf16x8*)(pBk[P][0] + (NI)*2048); \
  bb[1][NI] = *(const bf16x8*)(pBk[P][1] + (NI)*2048);

#define STAGE_A(P, HH, KT) \
  gload16(sA + ((HH)*2+0)*lda64 + (long)(KT)*64, (u16*)(lds + (P)*BUFB + (HH)*16384 + w*1024)); \
  gload16(sA + ((HH)*2+1)*lda64 + (long)(KT)*64, (u16*)(lds + (P)*BUFB + (HH)*16384 + 8192 + w*1024));

#define STAGE_B(P, HH, KT) \
  gload16(sB + ((HH)*2+0)*ldb64 + (long)(KT)*64, (u16*)(lds + (P)*BUFB + 32768 + (HH)*16384 + w*1024)); \
  gload16(sB + ((HH)*2+1)*ldb64 + (long)(KT)*64, (u16*)(lds + (P)*BUFB + 32768 + (HH)*16384 + 8192 + w*1024));

#define GEMM_TILE(P, PN, TA, TC) \
  RDA4(P,0,0) RDA4(P,1,0) \
  RDB1(P,0) RDB1(P,1) \
  STAGE_A(PN, 1, TA) \
  G_PHASE(MM8(0,0) MM8(0,1)) \
  RDB1(P,2) RDB1(P,3) \
  G_PHASE(MM8(0,2) MM8(0,3)) \
  RDA4(P,0,1) RDA4(P,1,1) \
  STAGE_B(P, 0, TC) \
  G_PHASE(MM8(4,0) MM8(4,1)) \
  STAGE_B(P, 1, TC) \
  STAGE_A(P, 0, TC) \
  asm volatile("s_waitcnt vmcnt(6)" ::: "memory"); \
  G_PHASE(MM8(4,2) MM8(4,3))

#define GEMM_TILE2(P, PN, TA, TC) \
  RDA4(P,0,0) RDA4(P,1,0) \
  RDB1(P,0) RDB1(P,1) \
  STAGE_A(PN, 0, TA) \
  STAGE_A(PN, 1, TA) \
  G_PHASE(MM8(0,0) MM8(0,1)) \
  RDA4(P,0,1) RDA4(P,1,1) \
  STAGE_B(P, 0, TC) \
  asm volatile("s_waitcnt vmcnt(2)" ::: "memory"); \
  G_PHASE(MM8(4,0) MM8(4,1))

template<int NF, int OUT>   // NF=4 -> BN=256 ; NF=2 -> BN=128
__global__ __launch_bounds__(512, 2) void gemm256(
    const u16* __restrict__ A, const u16* __restrict__ B, void* Cv,
    const float* __restrict__ bias, const float* __restrict__ bias2, int nsplit,
    const float* res, int K, int lda, int ldb, int ldc)
{
  extern __shared__ char lds[];
  constexpr int BN = NF * 64;
  constexpr int BUFB = (NF == 4) ? 65536 : 49152;   // A 32KB + B 32/16KB

  const int tid = threadIdx.x, w = tid >> 6, l = tid & 63;
  const int wm = w >> 2, wn = w & 3;

  // bijective XCD-chunked swizzle over COLUMN-MAJOR linear index
  const int gy = gridDim.y;
  const int nwg = gridDim.x * gy;
  const int orig = blockIdx.y * gridDim.x + blockIdx.x;
  const int q = nwg >> 3, r = nwg & 7;
  const int xcd = orig & 7, sidx = orig >> 3;
  const int wg = (xcd < r ? xcd * (q + 1) : r * (q + 1) + (xcd - r) * q) + sidx;
  const int bx = wg / gy, by = wg % gy;
  const long row0 = (long)by * 256, col0 = (long)bx * BN;

  // ---- LDS read base pointers (swizzled) ----
  const int g4 = l >> 4, h8 = l & 7, r16 = l & 15;
  const int cs0 = ((g4 ^ h8) << 4);
  const int cs1 = cs0 ^ 64;
  const char* pAk[2][2];
  const char* pBk[2][2];
  {
    const int aoff = wm * 16384 + r16 * 128;
    const int boff = 32768 + ((NF == 4) ? ((wn >> 1) * 16384 + (wn & 1) * 8192)
                                        : (wn * 4096)) + r16 * 128;
    pAk[0][0] = lds + aoff + cs0;        pAk[0][1] = lds + aoff + cs1;
    pAk[1][0] = pAk[0][0] + BUFB;        pAk[1][1] = pAk[0][1] + BUFB;
    pBk[0][0] = lds + boff + cs0;        pBk[0][1] = lds + boff + cs1;
    pBk[1][0] = pBk[0][0] + BUFB;        pBk[1][1] = pBk[0][1] + BUFB;
  }

  // ---- staging: pre-swizzled per-lane global source, linear LDS dest ----
  const long ldaL = lda, ldbL = ldb;
  const long lda64 = ldaL * 64, ldb64 = ldbL * 64;
  const int srow = w * 8 + (l >> 3);
  const int scol = ((h8 ^ (l >> 3)) << 3);
  const u16* sA = A + (row0 + srow) * ldaL + scol;
  const u16* sB = B + (col0 + srow) * ldbL + scol;

  f32x4 acc[8][4];
  #pragma unroll
  for (int m = 0; m < 8; m++)
    #pragma unroll
    for (int n = 0; n < 4; n++)
      #pragma unroll
      for (int j = 0; j < 4; j++) acc[m][n][j] = 0.f;

  bf16x8 aa[2][4], bb[2][4];

  const int NT = K >> 6;
  if constexpr (NF == 4) {
    STAGE_A(0,0,0) STAGE_A(0,1,0) STAGE_B(0,0,0) STAGE_B(0,1,0)
    STAGE_B(1,0,1) STAGE_B(1,1,1) STAGE_A(1,0,1)
    asm volatile("s_waitcnt vmcnt(6)" ::: "memory");
    __builtin_amdgcn_s_barrier();
    for (int t = 0; t < NT; t += 2) {
      const int ta = (t + 1 < NT) ? t + 1 : NT - 1;
      const int tb = (t + 2 < NT) ? t + 2 : NT - 1;
      const int tc = (t + 3 < NT) ? t + 3 : NT - 1;
      GEMM_TILE(0, 1, ta, tb)
      GEMM_TILE(1, 0, tb, tc)
    }
  } else {
    STAGE_A(0,0,0) STAGE_A(0,1,0) STAGE_B(0,0,0)
    STAGE_B(1,0,1)
    asm volatile("s_waitcnt vmcnt(2)" ::: "memory");
    __builtin_amdgcn_s_barrier();
    for (int t = 0; t < NT; t += 2) {
      const int ta = (t + 1 < NT) ? t + 1 : NT - 1;
      const int tb = (t + 2 < NT) ? t + 2 : NT - 1;
      const int tc = (t + 3 < NT) ? t + 3 : NT - 1;
      GEMM_TILE2(0, 1, ta, tb)
      GEMM_TILE2(1, 0, tb, tc)
    }
  }

  // ---- epilogue: C/D layout col = lane&15, row = (lane>>4)*4 + j [m89] ----
  const int cc = l & 15, cr = (l >> 4) * 4;
  #pragma unroll
  for (int mf = 0; mf < 8; mf++) {
    const long rrow = row0 + wm * 128 + mf * 16 + cr;
    if constexpr (OUT == 2) {
      #pragma unroll
      for (int nfp = 0; nfp < NF / 2; nfp++) {
        const long outc = (col0 >> 1) + wn * 32 + nfp * 16 + cc;
        const float b1 = bias[outc], b3 = bias2[outc];
        #pragma unroll
        for (int j = 0; j < 4; j++) {
          const float v1 = acc[mf][2 * nfp][j] + b1;
          const float v3 = acc[mf][2 * nfp + 1][j] + b3;
          const float o = v1 / (1.f + __expf(-v1)) * v3;
          ((u16*)Cv)[(rrow + j) * ldc + outc] = f2bf(o);
        }
      }
    } else {
      #pragma unroll
      for (int nf = 0; nf < 4 && nf < NF; nf++) {
        const long ccol = col0 + wn * (NF * 16) + nf * 16 + cc;
        float bb2 = 0.f;
        if (bias) bb2 = (ccol < nsplit) ? bias[ccol] : (bias2 ? bias2[ccol - nsplit] : 0.f);
        #pragma unroll
        for (int j = 0; j < 4; j++) {
          const long off = (rrow + j) * ldc + ccol;
          float v = acc[mf][nf][j] + bb2;
          if constexpr (OUT == 0) {
            if (res) v += res[off];
            ((float*)Cv)[off] = v;
          } else {
            ((u16*)Cv)[off] = f2bf(v);
          }
        }
      }
    }
  }
}

// ---------------- bf16 GEMM: C = A * B^T (128x128 tile) — scores / PV ----------------
// EPI=1: Cbf = bf16(acc*scale + bf2f(Cadd))   EPI=2: Cbf = bf16(acc*scale)
// causal!=0: skip fully-masked tiles.  kvar!=0: K_eff=(by+1)*128 (causal PV).
template<int EPI>
__global__ __launch_bounds__(256) void gemm_bt(
    const u16* __restrict__ A, const u16* __restrict__ B,
    u16* __restrict__ Cbf, const u16* __restrict__ Cadd,
    int K, int lda, int ldb, int ldc, float scale,
    long sAb, long sBb, int cInnerN, long cSO, long cSI, int causal, int kvar)
{
  if (causal && blockIdx.x > blockIdx.y) return;
  const int Keff = kvar ? (int)(blockIdx.y + 1) * 128 : K;

  __shared__ u16 As[128*32] __attribute__((aligned(16)));
  __shared__ u16 Bs[128*32] __attribute__((aligned(16)));
  const int tid  = threadIdx.x;
  const int wave = tid >> 6, lane = tid & 63;
  const int wm = wave >> 1, wn = wave & 1;
  const int z = blockIdx.z;
  const u16* Ab = A + (long)z * sAb;
  const u16* Bb = B + (long)z * sBb;
  const long cb = (long)(z / cInnerN) * cSO + (long)(z % cInnerN) * cSI;

  const int sr = lane >> 2;
  const int sc = (lane & 3) * 8;
  const int c0 = wave * 2, c1 = wave * 2 + 1;
  const u16* gA0 = Ab + (long)(blockIdx.y * 128 + c0 * 16 + sr) * lda + sc;
  const u16* gA1 = Ab + (long)(blockIdx.y * 128 + c1 * 16 + sr) * lda + sc;
  const u16* gB0 = Bb + (long)(blockIdx.x * 128 + c0 * 16 + sr) * ldb + sc;
  const u16* gB1 = Bb + (long)(blockIdx.x * 128 + c1 * 16 + sr) * ldb + sc;
  u16* lA0 = &As[c0 * 512]; u16* lA1 = &As[c1 * 512];
  u16* lB0 = &Bs[c0 * 512]; u16* lB1 = &Bs[c1 * 512];

  f32x4 acc[4][4];
  #pragma unroll
  for (int m = 0; m < 4; m++)
    #pragma unroll
    for (int n = 0; n < 4; n++)
      #pragma unroll
      for (int j = 0; j < 4; j++) acc[m][n][j] = 0.f;

  const int fr  = lane & 15;
  const int fg8 = (lane >> 4) * 8;

  for (int k0 = 0; k0 < Keff; k0 += 32) {
    __syncthreads();
    gload16(gA0 + k0, lA0);
    gload16(gA1 + k0, lA1);
    gload16(gB0 + k0, lB0);
    gload16(gB1 + k0, lB1);
    __syncthreads();

    bf16x8 af[4], bfr[4];
    #pragma unroll
    for (int m = 0; m < 4; m++)
      af[m] = *(const bf16x8*)&As[(wm * 64 + m * 16 + fr) * 32 + fg8];
    #pragma unroll
    for (int n = 0; n < 4; n++)
      bfr[n] = *(const bf16x8*)&Bs[(wn * 64 + n * 16 + fr) * 32 + fg8];

    #pragma unroll
    for (int m = 0; m < 4; m++)
      #pragma unroll
      for (int n = 0; n < 4; n++)
        acc[m][n] = __builtin_amdgcn_mfma_f32_16x16x32_bf16(af[m], bfr[n], acc[m][n], 0, 0, 0);
  }

  const int cc = lane & 15, cr = (lane >> 4) * 4;
  #pragma unroll
  for (int m = 0; m < 4; m++) {
    const int row = blockIdx.y * 128 + wm * 64 + m * 16 + cr;
    #pragma unroll
    for (int n = 0; n < 4; n++) {
      const int col = blockIdx.x * 128 + wn * 64 + n * 16 + cc;
      #pragma unroll
      for (int j = 0; j < 4; j++) {
        const long off = cb + (long)(row + j) * ldc + col;
        const float v = acc[m][n][j] * scale;
        if constexpr (EPI == 1) Cbf[off] = f2bf(v + bf2f(Cadd[off]));
        else                    Cbf[off] = f2bf(v);
      }
    }
  }
}

// ---------------- low-VGPR pack core: 4 rows/block, i-unroll 4 ----------------
__device__ __forceinline__ void pack_rows4(const float* __restrict__ w,
    const float* __restrict__ l2, const float* __restrict__ l1,
    u16* __restrict__ out, long srcRow0, long outRow0, int K) {
  __shared__ float l2s[4][16];
  if (threadIdx.x < 64) l2s[threadIdx.x >> 4][threadIdx.x & 15] =
      l2[(srcRow0 + (threadIdx.x >> 4)) * 16 + (threadIdx.x & 15)];
  __syncthreads();
  for (int c = threadIdx.x * 4; c < K; c += 1024) {
    float4 v0 = *(const float4*)(w + (srcRow0 + 0) * K + c);
    float4 v1 = *(const float4*)(w + (srcRow0 + 1) * K + c);
    float4 v2 = *(const float4*)(w + (srcRow0 + 2) * K + c);
    float4 v3 = *(const float4*)(w + (srcRow0 + 3) * K + c);
    #pragma unroll 4
    for (int i = 0; i < 16; i++) {
      const float4 lv = *(const float4*)(l1 + (long)i * K + c);
      const float a0 = l2s[0][i], a1 = l2s[1][i], a2 = l2s[2][i], a3 = l2s[3][i];
      v0.x += a0 * lv.x; v0.y += a0 * lv.y; v0.z += a0 * lv.z; v0.w += a0 * lv.w;
      v1.x += a1 * lv.x; v1.y += a1 * lv.y; v1.z += a1 * lv.z; v1.w += a1 * lv.w;
      v2.x += a2 * lv.x; v2.y += a2 * lv.y; v2.z += a2 * lv.z; v2.w += a2 * lv.w;
      v3.x += a3 * lv.x; v3.y += a3 * lv.y; v3.z += a3 * lv.z; v3.w += a3 * lv.w;
    }
    uint2 p0, p1, p2, p3;
    p0.x = pack2(v0.x, v0.y); p0.y = pack2(v0.z, v0.w);
    p1.x = pack2(v1.x, v1.y); p1.y = pack2(v1.z, v1.w);
    p2.x = pack2(v2.x, v2.y); p2.y = pack2(v2.z, v2.w);
    p3.x = pack2(v3.x, v3.y); p3.y = pack2(v3.z, v3.w);
    *(uint2*)(out + (outRow0 + 0) * K + c) = p0;
    *(uint2*)(out + (outRow0 + 1) * K + c) = p1;
    *(uint2*)(out + (outRow0 + 2) * K + c) = p2;
    *(uint2*)(out + (outRow0 + 3) * K + c) = p3;
  }
}

__global__ __launch_bounds__(256) void pack4(
    const float* w0, const float* a0, const float* b0, u16* o0,
    const float* w1, const float* a1, const float* b1, u16* o1,
    const float* w2, const float* a2, const float* b2, u16* o2,
    const float* w3, const float* a3, const float* b3, u16* o3) {
  const int sel = blockIdx.x >> 10;
  const long row0 = (long)(blockIdx.x & 1023) * 4;
  const float* w;  const float* l2; const float* l1; u16* out;
  switch (sel) {
    case 0:  w = w0; l2 = a0; l1 = b0; out = o0; break;
    case 1:  w = w1; l2 = a1; l1 = b1; out = o1; break;
    case 2:  w = w2; l2 = a2; l1 = b2; out = o2; break;
    default: w = w3; l2 = a3; l1 = b3; out = o3; break;
  }
  pack_rows4(w, l2, l1, out, row0, row0, 4096);
}

__global__ __launch_bounds__(256) void packw4(const float* __restrict__ w,
    const float* __restrict__ l2, const float* __restrict__ l1,
    u16* __restrict__ out, int K) {
  const long row0 = (long)blockIdx.x * 4;
  pack_rows4(w, l2, l1, out, row0, row0, K);
}

__global__ __launch_bounds__(256) void packw13_4(const float* __restrict__ w1,
    const float* __restrict__ l2_1, const float* __restrict__ l1_1,
    const float* __restrict__ w3,
    const float* __restrict__ l2_3, const float* __restrict__ l1_3,
    u16* __restrict__ out) {
  const long row0 = (long)blockIdx.x * 4;
  const int s = ((int)row0 >> 4) & 1;
  const long src0 = (row0 >> 5) * 16 + (row0 & 15);
  pack_rows4(s ? w3 : w1, s ? l2_3 : l2_1, s ? l1_3 : l1_1, out, src0, row0, 4096);
}

// ---------------- prep: rmsnorm tokens + prompt cvt + zero pad (grid 2304) ----------------
__global__ __launch_bounds__(256) void prep(const float* __restrict__ x, const float* __restrict__ w,
                                            const float* __restrict__ prompt, u16* __restrict__ out) {
  const int bid = blockIdx.x;
  if (bid < 2048) {
    const float4* xr = (const float4*)(x + (long)bid * 4096);
    const float4* wr = (const float4*)w;
    float4 v[4];
    float ss = 0.f;
    #pragma unroll
    for (int j = 0; j < 4; j++) {
      v[j] = xr[threadIdx.x + j * 256];
      ss += v[j].x * v[j].x + v[j].y * v[j].y + v[j].z * v[j].z + v[j].w * v[j].w;
    }
    #pragma unroll
    for (int off = 32; off; off >>= 1) ss += __shfl_xor(ss, off);
    __shared__ float wsum[4];
    if ((threadIdx.x & 63) == 0) wsum[threadIdx.x >> 6] = ss;
    __syncthreads();
    const float sc = rsqrtf((wsum[0] + wsum[1] + wsum[2] + wsum[3]) * (1.f / 4096.f) + EPSF);
    u16* orow = out + (long)bid * 4096;
    #pragma unroll
    for (int j = 0; j < 4; j++) {
      float4 wv = wr[threadIdx.x + j * 256];
      int idx = (threadIdx.x + j * 256) * 4;
      uint2 p;
      p.x = pack2(v[j].x * sc * wv.x, v[j].y * sc * wv.y);
      p.y = pack2(v[j].z * sc * wv.z, v[j].w * sc * wv.w);
      *(uint2*)&orow[idx] = p;
    }
  } else if (bid < 2088) {
    const int r = bid - 2048;
    const float4* src = (const float4*)(prompt + (long)r * 4096);
    u16* dst = out + (long)(2048 + r) * 4096;
    #pragma unroll
    for (int j = 0; j < 4; j++) {
      float4 v = src[threadIdx.x + j * 256];
      int idx = (threadIdx.x + j * 256) * 4;
      uint2 p; p.x = pack2(v.x, v.y); p.y = pack2(v.z, v.w);
      *(uint2*)&dst[idx] = p;
    }
  } else {
    u16* dst = out + (long)bid * 4096 + threadIdx.x * 16;
    i32x4 z; z[0] = 0; z[1] = 0; z[2] = 0; z[3] = 0;
    *(i32x4*)dst = z;
    *(i32x4*)(dst + 8) = z;
  }
}

// ---------------- fused prompt LoRA subtract on bf16 xqkv K/V cols (grid 40) ----------------
__global__ __launch_bounds__(256) void lorap(const u16* __restrict__ Ap,
    const float* __restrict__ L1k, const float* __restrict__ L2k,
    const float* __restrict__ L1v, const float* __restrict__ L2v,
    u16* __restrict__ xqkv) {
  const int row = blockIdx.x;
  const int lane = threadIdx.x & 63, wave = threadIdx.x >> 6;
  __shared__ float tk[16], tv[16];
  const u16* a = Ap + (long)row * 4096;
  {
    const float* k0 = L1k + (long)(wave * 4 + 0) * 4096;
    const float* k1 = L1k + (long)(wave * 4 + 1) * 4096;
    const float* k2 = L1k + (long)(wave * 4 + 2) * 4096;
    const float* k3 = L1k + (long)(wave * 4 + 3) * 4096;
    const float* v0 = L1v + (long)(wave * 4 + 0) * 4096;
    const float* v1 = L1v + (long)(wave * 4 + 1) * 4096;
    const float* v2 = L1v + (long)(wave * 4 + 2) * 4096;
    const float* v3 = L1v + (long)(wave * 4 + 3) * 4096;
    float ak0 = 0, ak1 = 0, ak2 = 0, ak3 = 0;
    float av0 = 0, av1 = 0, av2 = 0, av3 = 0;
    for (int k = lane; k < 4096; k += 64) {
      const float av = bf2f(a[k]);
      ak0 += av * k0[k]; ak1 += av * k1[k]; ak2 += av * k2[k]; ak3 += av * k3[k];
      av0 += av * v0[k]; av1 += av * v1[k]; av2 += av * v2[k]; av3 += av * v3[k];
    }
    #pragma unroll
    for (int off = 32; off; off >>= 1) {
      ak0 += __shfl_down(ak0, off); ak1 += __shfl_down(ak1, off);
      ak2 += __shfl_down(ak2, off); ak3 += __shfl_down(ak3, off);
      av0 += __shfl_down(av0, off); av1 += __shfl_down(av1, off);
      av2 += __shfl_down(av2, off); av3 += __shfl_down(av3, off);
    }
    if (lane == 0) {
      tk[wave * 4 + 0] = ak0; tk[wave * 4 + 1] = ak1;
      tk[wave * 4 + 2] = ak2; tk[wave * 4 + 3] = ak3;
      tv[wave * 4 + 0] = av0; tv[wave * 4 + 1] = av1;
      tv[wave * 4 + 2] = av2; tv[wave * 4 + 3] = av3;
    }
  }
  __syncthreads();
  u16* xr = xqkv + (long)(2048 + row) * 12288;
  for (int col = threadIdx.x; col < 4096; col += 256) {
    float addk = 0.f, addv = 0.f;
    const float* lk = L2k + (long)col * 16;
    const float* lv = L2v + (long)col * 16;
    #pragma unroll
    for (int r = 0; r < 16; r++) { addk += tk[r] * lk[r]; addv += tv[r] * lv[r]; }
    xr[4096 + col] = f2bf(bf2f(xr[4096 + col]) - addk);
    xr[8192 + col] = f2bf(bf2f(xr[8192 + col]) - addv);
  }
}

// ---------------- layout: rope (2048) + vtrans (8192) + extract_prompt (40) ----------------
__global__ __launch_bounds__(256) void layout(const u16* __restrict__ xqkv,
    const float* __restrict__ cosT, const float* __restrict__ sinT,
    u16* __restrict__ qbf, u16* __restrict__ kbf, u16* __restrict__ vt,
    u16* __restrict__ pk, u16* __restrict__ pv) {
  const int bid = blockIdx.x;
  if (bid < 2048) {
    const int s = bid & 511, b = bid >> 9;
    for (int pp = threadIdx.x; pp < 2048; pp += 256) {
      const int h = pp >> 6, ip = pp & 63;
      const float c = cosT[s * 64 + ip], sn = sinT[s * 64 + ip];
      const long src = (long)bid * 12288 + h * 128 + ip * 2;
      const u32 qv = *(const u32*)(xqkv + src);
      const u32 kv = *(const u32*)(xqkv + src + 4096);
      const float qx = bf2f((u16)qv), qy = bf2f((u16)(qv >> 16));
      const float kx = bf2f((u16)kv), ky = bf2f((u16)(kv >> 16));
      const long dst = ((long)(b * 32 + h) * 512 + s) * 128 + ip * 2;
      *(u32*)&qbf[dst] = pack2(qx * c - qy * sn, qx * sn + qy * c);
      *(u32*)&kbf[dst] = pack2(kx * c - ky * sn, kx * sn + ky * c);
    }
  } else if (bid < 10240) {
    const int idx = bid - 2048;
    const int s0 = (idx & 15) * 32, d0 = ((idx >> 4) & 3) * 32, bh = idx >> 6;
    const int b = bh >> 5, h = bh & 31;
    __shared__ u16 tile[32][33];
    const int tx = threadIdx.x & 31, ty = threadIdx.x >> 5;
    #pragma unroll
    for (int j = 0; j < 4; j++) {
      const int s = s0 + ty + j * 8;
      tile[ty + j * 8][tx] = xqkv[(long)(b * 512 + s) * 12288 + 8192 + h * 128 + d0 + tx];
    }
    __syncthreads();
    #pragma unroll
    for (int j = 0; j < 4; j++) {
      const int d = d0 + ty + j * 8;
      vt[((long)bh * 128 + d) * 512 + s0 + tx] = tile[tx][ty + j * 8];
    }
  } else {
    const int rp = bid - 10240;
    const int b = rp / 10, p = rp % 10;
    const u16* src = xqkv + (long)(2048 + rp) * 12288;
    for (int col = threadIdx.x * 2; col < 4096; col += 512) {
      const int h = col >> 7, d = col & 127;
      const long dst = ((long)(b * 32 + h) * 10 + p) * 128 + d;
      *(u32*)&pk[dst] = *(const u32*)&src[4096 + col];
      *(u32*)&pv[dst] = *(const u32*)&src[8192 + col];
    }
  }
}

// ---------------- smpa: softmax over bf16 scores (16384) + prompt attention (16384) ----------------
__global__ __launch_bounds__(256) void smpa(const u16* __restrict__ sc, u16* __restrict__ P,
    const u16* __restrict__ qbf, const u16* __restrict__ pk, const u16* __restrict__ pv,
    const float* __restrict__ gate, const float* __restrict__ ngate, u16* __restrict__ attnp) {
  const int bid = blockIdx.x;
  const int lane = threadIdx.x & 63;
  if (bid < 16384) {
    const int r = bid * 4 + (threadIdx.x >> 6);
    const int q = r & 511;
    const u16* srow = sc + (long)r * 512 + lane * 8;
    i32x4 raw = *(const i32x4*)srow;
    float v[8]; float m = -3e38f;
    #pragma unroll
    for (int j = 0; j < 8; j++) {
      const u32 u = (u32)raw[j >> 1];
      const float val = bf2f((j & 1) ? (u16)(u >> 16) : (u16)u);
      const int col = lane * 8 + j;
      v[j] = (col <= q) ? val : -3e38f;
      m = fmaxf(m, v[j]);
    }
    #pragma unroll
    for (int off = 32; off; off >>= 1) m = fmaxf(m, __shfl_xor(m, off));
    float sum = 0.f;
    #pragma unroll
    for (int j = 0; j < 8; j++) { v[j] = __expf(v[j] - m); sum += v[j]; }
    #pragma unroll
    for (int off = 32; off; off >>= 1) sum += __shfl_xor(sum, off);
    const float inv = 1.f / sum;
    i32x4 o;
    o[0] = (int)pack2(v[0] * inv, v[1] * inv); o[1] = (int)pack2(v[2] * inv, v[3] * inv);
    o[2] = (int)pack2(v[4] * inv, v[5] * inv); o[3] = (int)pack2(v[6] * inv, v[7] * inv);
    *(i32x4*)(P + (long)r * 512 + lane * 8) = o;
  } else {
    const int r = (bid - 16384) * 4 + (threadIdx.x >> 6);
    const int bh = r >> 9, q = r & 511, b = bh >> 5, h = bh & 31;
    const u32 qraw = *(const u32*)&qbf[(long)r * 128 + lane * 2];
    const float q0 = bf2f((u16)qraw), q1 = bf2f((u16)(qraw >> 16));
    float s[10];
    #pragma unroll
    for (int p = 0; p < 10; p++) {
      const u32 kraw = *(const u32*)&pk[((long)bh * 10 + p) * 128 + lane * 2];
      float d = q0 * bf2f((u16)kraw) + q1 * bf2f((u16)(kraw >> 16));
      #pragma unroll
      for (int off = 32; off; off >>= 1) d += __shfl_xor(d, off);
      s[p] = d * SCALEF;
    }
    float m = s[0];
    #pragma unroll
    for (int p = 1; p < 10; p++) m = fmaxf(m, s[p]);
    float sum = 0.f;
    #pragma unroll
    for (int p = 0; p < 10; p++) { s[p] = __expf(s[p] - m); sum += s[p]; }
    const float gt = tanhf(gate[h]) * ngate[0] / sum;
    float o0 = 0.f, o1 = 0.f;
    #pragma unroll
    for (int p = 0; p < 10; p++) {
      const u32 vraw = *(const u32*)&pv[((long)bh * 10 + p) * 128 + lane * 2];
      o0 += s[p] * bf2f((u16)vraw); o1 += s[p] * bf2f((u16)(vraw >> 16));
    }
    *(u32*)&attnp[(long)(b * 512 + q) * 4096 + h * 128 + lane * 2] = pack2(gt * o0, gt * o1);
  }
}

// =====================================================================================
extern "C" void kernel_launch(void* const* d_in, const int* in_sizes, int n_in,
                              void* d_out, int out_size, void* d_ws, size_t ws_size,
                              hipStream_t stream) {
  const float* x      = (const float*)d_in[0];
  const float* prompt = (const float*)d_in[1];
  const float* fcos   = (const float*)d_in[5];
  const float* fsin   = (const float*)d_in[6];
  const float* wq     = (const float*)d_in[7];
  const float* wq_b   = (const float*)d_in[8];
  const float* wk     = (const float*)d_in[9];
  const float* wv     = (const float*)d_in[10];
  const float* wo     = (const float*)d_in[11];
  const float* wo_b   = (const float*)d_in[12];
  const float* lq1    = (const float*)d_in[13];
  const float* lq2    = (const float*)d_in[14];
  const float* lk1    = (const float*)d_in[15];
  const float* lk2    = (const float*)d_in[16];
  const float* lv1    = (const float*)d_in[17];
  const float* lv2    = (const float*)d_in[18];
  const float* lo1    = (const float*)d_in[19];
  const float* lo2    = (const float*)d_in[20];
  const float* gate   = (const float*)d_in[21];
  const float* ngate  = (const float*)d_in[22];
  const float* anw    = (const float*)d_in[23];
  const float* fnw    = (const float*)d_in[24];
  const float* w1     = (const float*)d_in[25];
  const float* w1_b   = (const float*)d_in[26];
  const float* w2     = (const float*)d_in[27];
  const float* w2_b   = (const float*)d_in[28];
  const float* w3     = (const float*)d_in[29];
  const float* w3_b   = (const float*)d_in[30];
  const float* fl1a   = (const float*)d_in[31];
  const float* fl1b   = (const float*)d_in[32];
  const float* fl2a   = (const float*)d_in[33];
  const float* fl2b   = (const float*)d_in[34];
  const float* fl3a   = (const float*)d_in[35];
  const float* fl3b   = (const float*)d_in[36];
  float* out = (float*)d_out;

  char* base = (char*)d_ws;
  u16* Wq  = (u16*)(base + 0L);          // Wq|Wk|Wv contiguous -> fused QKV B (12288 x 4096)
  u16* Wo  = (u16*)(base + 100663296L);
  u16* W13 = (u16*)(base + 134217728L);  // 22016 x 4096, w1/w3 interleaved by 16 rows
  u16* W2  = (u16*)(base + 314572800L);
  u16* Abf = (u16*)(base + 404750336L);  // 2304 x 4096 bf16 (tokens + prompt + zero pad)
  const long SP = 423624704L;
  // region X (time-multiplexed): xqkv (2304x12288 bf16, 56.6MB) -> scores16 (67MB) -> obf (45MB)
  u16*   xqkv     = (u16*)(base + SP);
  u16*   scores16 = (u16*)(base + SP);
  u16*   obf      = (u16*)(base + SP);
  u16*   qbf      = (u16*)(base + SP + 134217728L);
  u16*   kbf      = (u16*)(base + SP + 150994944L);
  u16*   vt       = (u16*)(base + SP + 167772160L);
  u16*   pk       = (u16*)(base + SP + 184549376L);
  u16*   pv       = (u16*)(base + SP + 184877056L);
  u16*   Pbf      = (u16*)(base + SP + 185204736L);
  u16*   attnp    = (u16*)(base + SP + 252313600L);  // bf16 (16.8MB)
  u16*   attnbf   = (u16*)(base + SP + 285868032L);
  u16*   gbf      = (u16*)(base + SP + 302645248L);
  const long TOTAL = SP + 319422464L + 131072L;
  if ((long)ws_size < TOTAL) return;

  dim3 blk(256);
  {
    auto f41 = gemm256<4, 1>; auto f42 = gemm256<4, 2>; auto f2 = gemm256<2, 0>;
    (void)hipFuncSetAttribute((const void*)f41, hipFuncAttributeMaxDynamicSharedMemorySize, 131072);
    (void)hipFuncSetAttribute((const void*)f42, hipFuncAttributeMaxDynamicSharedMemorySize, 131072);
    (void)hipFuncSetAttribute((const void*)f2,  hipFuncAttributeMaxDynamicSharedMemorySize, 98304);
  }

  // 1) pack weights (LoRA folded): W' = W + l2 @ l1
  pack4<<<4096, blk, 0, stream>>>(wq, lq2, lq1, Wq,
                                  wk, lk2, lk1, Wq + 16777216L,
                                  wv, lv2, lv1, Wq + 33554432L,
                                  wo, lo2, lo1, Wo);
  packw13_4<<<5504, blk, 0, stream>>>(w1, fl1b, fl1a, w3, fl3b, fl3a, W13);
  packw4<<<1024, blk, 0, stream>>>(w2, fl2b, fl2a, W2, 11008);

  // 2) A matrix: rms(x) tokens + prompt cvt + zero pad
  prep<<<2304, blk, 0, stream>>>(x, anw, prompt, Abf);

  // 3) fused QKV projection incl. prompt rows (M=2304, N=12288, bf16 out); wq_b on Q cols
  gemm256<4, 1><<<dim3(48, 9), 512, 131072, stream>>>(Abf, Wq, xqkv, wq_b, nullptr, 4096,
      nullptr, 4096, 4096, 4096, 12288);
  // subtract LoRA from prompt K/V rows (reference has no LoRA on prompt)
  lorap<<<40, blk, 0, stream>>>(Abf + 2048L * 4096, lk1, lk2, lv1, lv2, xqkv);

  // 4) RoPE + V transpose + prompt extract (one dispatch)
  layout<<<10280, blk, 0, stream>>>(xqkv, fcos, fsin, qbf, kbf, vt, pk, pv);

  // 5) attention (causal-aware; bf16 scores overlay dead xqkv)
  gemm_bt<2><<<dim3(4, 4, 128), blk, 0, stream>>>(qbf, kbf, scores16, nullptr,
      128, 128, 128, 512, SCALEF, 65536L, 65536L, 1, 262144L, 0, 1, 0);
  smpa<<<32768, blk, 0, stream>>>(scores16, Pbf, qbf, pk, pv, gate, ngate, attnp);
  gemm_bt<1><<<dim3(1, 4, 128), blk, 0, stream>>>(Pbf, vt, attnbf, attnp,
      512, 512, 512, 4096, 1.f, 262144L, 65536L, 32, 2097152L, 128L, 0, 1);

  // 6) output projection (+bias +residual x) -> h2 in d_out
  gemm256<2, 0><<<dim3(32, 8), 512, 98304, stream>>>(attnbf, Wo, out, wo_b, nullptr, 1 << 30,
      x, 4096, 4096, 4096, 4096);

  // 7) FFN: rms -> fused W1|W3 GEMM with swiglu epilogue -> obf -> W2 (+bias +res h2)
  prep<<<2048, blk, 0, stream>>>(out, fnw, nullptr, gbf);
  gemm256<4, 2><<<dim3(86, 8), 512, 131072, stream>>>(gbf, W13, obf, w1_b, w3_b, 0,
      nullptr, 4096, 4096, 4096, 11008);
  gemm256<2, 0><<<dim3(32, 8), 512, 98304, stream>>>(obf, W2, out, w2_b, nullptr, 1 << 30,
      out, 11008, 11008, 11008, 4096);
}